// Round 12
// baseline (849.368 us; speedup 1.0000x reference)
//
#include <hip/hip_runtime.h>
#include <hip/hip_bf16.h>

typedef __attribute__((ext_vector_type(8))) short short8_t;
typedef __attribute__((ext_vector_type(8))) unsigned short ushort8_t;
typedef __attribute__((ext_vector_type(4))) float f32x4;

#define SCALE 0.125f   // 64^-0.5

__device__ __forceinline__ unsigned short f32_to_bf16_rne(float f) {
  unsigned int u = __float_as_uint(f);
  unsigned int r = 0x7FFFu + ((u >> 16) & 1u);
  return (unsigned short)((u + r) >> 16);
}
__device__ __forceinline__ float bf16_to_f32(unsigned short s) {
  return __uint_as_float((unsigned)s << 16);
}
// bank-spread swizzle for 64B rows (32 j * bf16): slot' = slot ^ swz(row)
__device__ __forceinline__ int swz(int i) { return (i + (i >> 2)) & 3; }

// ---------------- cast x (fp32 -> bf16) ----------------
__global__ __launch_bounds__(256) void cast_x_kernel(const float4* __restrict__ in,
                                                     ushort4* __restrict__ out, int n4) {
  int i = blockIdx.x * 256 + threadIdx.x;
  if (i < n4) {
    float4 v = in[i];
    ushort4 o;
    o.x = f32_to_bf16_rne(v.x); o.y = f32_to_bf16_rne(v.y);
    o.z = f32_to_bf16_rne(v.z); o.w = f32_to_bf16_rne(v.w);
    out[i] = o;
  }
}

// ---------------- transpose + cast weights: in R x C fp32 -> out C x R bf16 ----------------
__global__ __launch_bounds__(256) void transpose_cast_kernel(const float* __restrict__ in,
                                                             unsigned short* __restrict__ out,
                                                             int R, int C) {
  __shared__ float tile[32][33];
  int c0 = blockIdx.x * 32, r0 = blockIdx.y * 32;
  int tx = threadIdx.x & 31, ty = threadIdx.x >> 5;  // 32 x 8
  #pragma unroll
  for (int i = ty; i < 32; i += 8)
    tile[i][tx] = in[(long)(r0 + i) * C + c0 + tx];
  __syncthreads();
  #pragma unroll
  for (int i = ty; i < 32; i += 8)
    out[(long)(c0 + i) * R + r0 + tx] = f32_to_bf16_rne(tile[tx][i]);
}

// ---------------- transpose V (LINEAR j): Vt[b][h][d][j] = KV[b*1024+j][768+h*64+d] ----------------
// fused_pv reads V B-frags directly from global (16B contiguous in j), so the
// layout is plain row-major [d][1024 j] -- no swizzle.
__global__ __launch_bounds__(256) void transpose_v_kernel(const unsigned short* __restrict__ KV,
                                                          unsigned short* __restrict__ Vt) {
  __shared__ unsigned short tile[64][72];
  const int j0 = blockIdx.x * 64, h = blockIdx.y, b = blockIdx.z;
  const int tid = threadIdx.x;
  for (int c = tid; c < 512; c += 256) {
    int j = c >> 3, dp = (c & 7) * 8;
    *(ushort8_t*)&tile[j][dp] =
        *(const ushort8_t*)&KV[(long)(b * 1024 + j0 + j) * 1536 + 768 + h * 64 + dp];
  }
  __syncthreads();
  for (int c = tid; c < 512; c += 256) {
    int d = c >> 3, jp = (c & 7) * 8;
    ushort8_t v;
    #pragma unroll
    for (int t = 0; t < 8; t++) v[t] = tile[jp + t][d];
    *(ushort8_t*)&Vt[((long)(b * 12 + h) * 64 + d) * 1024 + j0 + jp] = v;
  }
}

// ---------------- NT GEMM (projections / out-proj). SUM2: A := A + A2 (bf16) ----------------
template <int BM, int BN, bool OUT_F32, bool BIAS, bool SUM2>
__global__ __launch_bounds__(256) void gemm_nt(const unsigned short* __restrict__ A,
                                               const unsigned short* __restrict__ A2, int lda,
                                               const unsigned short* __restrict__ B, int ldb,
                                               void* __restrict__ Cv, int ldc,
                                               const float* __restrict__ bias,
                                               int M, int N, int K) {
  constexpr int BK = 32;
  constexpr int LDT = BK + 8;
  __shared__ unsigned short As[BM][LDT];
  __shared__ unsigned short Bs[BN][LDT];
  const int m0 = blockIdx.y * BM;
  const int n0 = blockIdx.x * BN;
  const int tid = threadIdx.x;
  const int lane = tid & 63;
  const int w = tid >> 6;
  constexpr int WM = BM / 2, WN = BN / 2;
  constexpr int FM = WM / 16, FN = WN / 16;
  const int wr = w >> 1, wc = w & 1;

  f32x4 acc[FM][FN];
  #pragma unroll
  for (int a = 0; a < FM; a++)
    #pragma unroll
    for (int b2 = 0; b2 < FN; b2++) acc[a][b2] = (f32x4){0.f, 0.f, 0.f, 0.f};

  const int rl = lane & 15;
  const int kq = (lane >> 4) * 8;

  for (int k0 = 0; k0 < K; k0 += BK) {
    __syncthreads();
    for (int c = tid; c < BM * (BK / 8); c += 256) {
      int row = c >> 2, kp = (c & 3) * 8;
      ushort8_t v = *(const ushort8_t*)&A[(long)(m0 + row) * lda + k0 + kp];
      if (SUM2) {
        ushort8_t v2 = *(const ushort8_t*)&A2[(long)(m0 + row) * lda + k0 + kp];
        #pragma unroll
        for (int x = 0; x < 8; ++x)
          v[x] = f32_to_bf16_rne(bf16_to_f32(v[x]) + bf16_to_f32(v2[x]));
      }
      *(ushort8_t*)&As[row][kp] = v;
    }
    for (int c = tid; c < BN * (BK / 8); c += 256) {
      int row = c >> 2, kp = (c & 3) * 8;
      *(ushort8_t*)&Bs[row][kp] = *(const ushort8_t*)&B[(long)(n0 + row) * ldb + k0 + kp];
    }
    __syncthreads();
    short8_t af[FM], bfr[FN];
    #pragma unroll
    for (int fm = 0; fm < FM; fm++) af[fm] = *(const short8_t*)&As[wr * WM + fm * 16 + rl][kq];
    #pragma unroll
    for (int fn = 0; fn < FN; fn++) bfr[fn] = *(const short8_t*)&Bs[wc * WN + fn * 16 + rl][kq];
    #pragma unroll
    for (int fm = 0; fm < FM; fm++)
      #pragma unroll
      for (int fn = 0; fn < FN; fn++)
        acc[fm][fn] = __builtin_amdgcn_mfma_f32_16x16x32_bf16(af[fm], bfr[fn], acc[fm][fn], 0, 0, 0);
  }

  const int rq4 = (lane >> 4) * 4;
  #pragma unroll
  for (int fm = 0; fm < FM; fm++)
    #pragma unroll
    for (int fn = 0; fn < FN; fn++)
      #pragma unroll
      for (int j = 0; j < 4; j++) {
        int row = m0 + wr * WM + fm * 16 + rq4 + j;
        int col = n0 + wc * WN + fn * 16 + rl;
        float v = acc[fm][fn][j];
        if (BIAS) v += bias[col];
        if (OUT_F32)
          ((float*)Cv)[(long)row * ldc + col] = v;
        else
          ((unsigned short*)Cv)[(long)row * ldc + col] = f32_to_bf16_rne(v);
      }
}

// ---------------- Pass A: QK^T -> dots(LDS) -> mix+exp -> row sums ONLY ----------------
// Round-10 qk with the E store DELETED: rounds 8-10 proved qk time was pinned
// by the E write volume (WRITE_SIZE byte-exact 2x(E+Lpart) across 3 different
// structures) while compute is ~free. E is now recomputed in fused_pv instead.
// Block = (jt, it2, zc=b): 32 i x 32 j tile, writes only Lpart (12.6 MB total).
__global__ __launch_bounds__(256, 1) void qk_sum_kernel(
    const unsigned short* __restrict__ Qb, const unsigned short* __restrict__ KVb,
    const float* __restrict__ mix_pre, float* __restrict__ Lpart) {
  __shared__ unsigned short Dbuf[12 * 32 * 44];  // 33 KB dots (bf16)
  __shared__ float mpre_t[144];                  // transposed [g][h], *SCALE
  const int jt = blockIdx.x, it2 = blockIdx.y, zc = blockIdx.z;
  const int b = zc;
  const int tid = threadIdx.x, lane = tid & 63, w = tid >> 6;
  const int r15 = lane & 15, q = lane >> 4;
  if (tid < 144) {
    int g = tid / 12, h = tid - g * 12;
    mpre_t[tid] = mix_pre[h * 12 + g] * SCALE;
  }

  // ---- phase 1: per-head QK^T -> dots ----
  const int isel = w >> 1, jsel = w & 1;
  const long qrow = (long)(b * 1024 + it2 * 32 + isel * 16 + r15) * 768 + q * 8;
  const long krow = (long)(b * 1024 + jt * 32 + jsel * 16 + r15) * 1536 + q * 8;
  const int jcol = jsel * 16 + r15;
  for (int h = 0; h < 12; ++h) {
    const int kb = h * 64;
    short8_t a0 = *(const short8_t*)&Qb[qrow + kb];
    short8_t a1 = *(const short8_t*)&Qb[qrow + kb + 32];
    short8_t b0 = *(const short8_t*)&KVb[krow + kb];
    short8_t b1 = *(const short8_t*)&KVb[krow + kb + 32];
    f32x4 h0 = {0.f, 0.f, 0.f, 0.f};
    h0 = __builtin_amdgcn_mfma_f32_16x16x32_bf16(a0, b0, h0, 0, 0, 0);
    h0 = __builtin_amdgcn_mfma_f32_16x16x32_bf16(a1, b1, h0, 0, 0, 0);
    #pragma unroll
    for (int e = 0; e < 4; ++e) {
      int il = isel * 16 + q * 4 + e;
      Dbuf[h * 1408 + il * 44 + jcol] = f32_to_bf16_rne(h0[e]);
    }
  }
  __syncthreads();

  // ---- phase 2: mix + exp + row-sum -> Lpart ----
  const int i_loc = tid >> 3;   // 0..31
  const int jg = tid & 7;       // j quad: j = jg*4 .. +3

  float dvf[12][4];
  #pragma unroll
  for (int h = 0; h < 12; ++h) {
    ushort4 dv = *(const ushort4*)&Dbuf[h * 1408 + i_loc * 44 + jg * 4];
    dvf[h][0] = bf16_to_f32(dv.x); dvf[h][1] = bf16_to_f32(dv.y);
    dvf[h][2] = bf16_to_f32(dv.z); dvf[h][3] = bf16_to_f32(dv.w);
  }

  #pragma unroll
  for (int g = 0; g < 12; ++g) {
    float a0 = 0.f, a1 = 0.f, a2 = 0.f, a3 = 0.f;
    #pragma unroll
    for (int h = 0; h < 12; ++h) {
      const float wgt = mpre_t[g * 12 + h];
      a0 += wgt * dvf[h][0]; a1 += wgt * dvf[h][1];
      a2 += wgt * dvf[h][2]; a3 += wgt * dvf[h][3];
    }
    a0 = __expf(a0); a1 = __expf(a1); a2 = __expf(a2); a3 = __expf(a3);
    float s = a0 + a1 + a2 + a3;
    s += __shfl_xor(s, 1);
    s += __shfl_xor(s, 2);
    s += __shfl_xor(s, 4);
    if (jg == (g & 7))
      Lpart[((long)(zc * 32 + jt) * 12 + g) * 1024 + it2 * 32 + i_loc] = s;
  }
}

// ---------------- Y: invl[zc][g][i] = 1 / sum_jt Lpart ----------------
__global__ __launch_bounds__(256) void lsum_kernel(const float* __restrict__ Lpart,
                                                   float* __restrict__ invl, int nb) {
  int id = blockIdx.x * 256 + threadIdx.x;
  if (id >= nb * 12288) return;
  int z = id / 12288, r = id - z * 12288;
  float s = 0.f;
  #pragma unroll 4
  for (int jt = 0; jt < 32; ++jt) s += Lpart[((long)(z * 32 + jt)) * 12288 + r];
  invl[id] = 1.f / s;
}

// ---------------- Pass B: fused QK-recompute + mix + exp*invl + mpost + PV ----------------
// Block = (it16, jh, zc=b): 16 i-rows, all 12 g2, j-half of 512. Loop 16 j-tiles:
//   QK: wave w owns h-trio {3w..3w+2}; A-frags hoisted (24 VGPR); B-frags (K)
//       direct from global (L2-resident); 12 MFMA -> raw dots bf16 in Dbuf.
//   mix: thread (i, j-pair): 12h dots -> 12g logits -> exp * invl -> Ebuf bf16.
//   P'': wave's 3 g2 x mpost (36 wave-uniform scalars) -> Pbuf (swizzled).
//   PV:  A-frag from Pbuf, B-frag V DIRECT from global (staging V in LDS saves
//        zero L2 traffic; dropping Vbuf cuts LDS 89->41 KB -> 3 blocks/CU).
// Dots bf16-rounded identically to pass A -> l and P'' numerics = round 10.
__global__ __launch_bounds__(256, 1) void fused_pv_kernel(
    const unsigned short* __restrict__ Qb, const unsigned short* __restrict__ KVb,
    const unsigned short* __restrict__ Vt, const float* __restrict__ invl,
    const float* __restrict__ mix_pre, const float* __restrict__ mix_post,
    unsigned short* __restrict__ AOp0, unsigned short* __restrict__ AOp1) {
  __shared__ unsigned short Dbuf[12][16][34];  // raw dots (pad 34: 2-way max)
  __shared__ unsigned short Ebuf[12][16][40];  // e~ = exp*invl (stride 80B, 16B-aligned reads)
  __shared__ unsigned short Pbuf[12 * 512];    // P'' [g2][16 i][32 j] swizzled
  __shared__ float mpre_t[144];
  const int it = blockIdx.x, jh = blockIdx.y, zc = blockIdx.z;
  const int b = zc;
  const int tid = threadIdx.x, lane = tid & 63, w = tid >> 6;
  const int r15 = lane & 15, q = lane >> 4;
  if (tid < 144) {
    int g = tid / 12, h = tid - g * 12;
    mpre_t[tid] = mix_pre[h * 12 + g] * SCALE;
  }

  // hoisted QK A-frags: wave's h-trio, rows i = it*16 + r15
  const int h0 = w * 3;
  const long qbase = (long)(b * 1024 + it * 16 + r15) * 768;
  short8_t qf[3][2];
  #pragma unroll
  for (int hh = 0; hh < 3; ++hh) {
    qf[hh][0] = *(const short8_t*)&Qb[qbase + (h0 + hh) * 64 + q * 8];
    qf[hh][1] = *(const short8_t*)&Qb[qbase + (h0 + hh) * 64 + 32 + q * 8];
  }

  // wave-uniform mpost weights for its 3 g2
  float wpost[3][12];
  #pragma unroll
  for (int g = 0; g < 12; ++g)
    #pragma unroll
    for (int r = 0; r < 3; ++r) wpost[r][g] = mix_post[g * 12 + w * 3 + r];

  // per-thread invl for the mix stage (i = tid&15)
  const int i_mix = tid & 15;
  const int jp = tid >> 4;          // 0..15 -> j-pair
  const int jslot = (tid >> 4) & 3; // P''-stage 8-j slot
  float il[12];
  #pragma unroll
  for (int g = 0; g < 12; ++g) il[g] = invl[(zc * 12 + g) * 1024 + it * 16 + i_mix];

  f32x4 acc[3][4];
  #pragma unroll
  for (int gl = 0; gl < 3; ++gl)
    #pragma unroll
    for (int df = 0; df < 4; ++df) acc[gl][df] = (f32x4){0.f, 0.f, 0.f, 0.f};

  const long vbase = (long)(b * 12) * 64 * 1024;

  for (int t = 0; t < 16; ++t) {
    const int j0 = (jh * 16 + t) * 32;

    // ---- QK: dots for wave's 3 h over 16i x 32j ----
    #pragma unroll
    for (int hh = 0; hh < 3; ++hh) {
      #pragma unroll
      for (int jhf = 0; jhf < 2; ++jhf) {
        const long kr = (long)(b * 1024 + j0 + jhf * 16 + r15) * 1536 + (h0 + hh) * 64 + q * 8;
        short8_t b0 = *(const short8_t*)&KVb[kr];
        short8_t b1 = *(const short8_t*)&KVb[kr + 32];
        f32x4 d = {0.f, 0.f, 0.f, 0.f};
        d = __builtin_amdgcn_mfma_f32_16x16x32_bf16(qf[hh][0], b0, d, 0, 0, 0);
        d = __builtin_amdgcn_mfma_f32_16x16x32_bf16(qf[hh][1], b1, d, 0, 0, 0);
        #pragma unroll
        for (int e = 0; e < 4; ++e)
          Dbuf[h0 + hh][q * 4 + e][jhf * 16 + r15] = f32_to_bf16_rne(d[e]);
      }
    }
    __syncthreads();  // dots ready (also guards Dbuf reuse: >=1 barrier since last read)

    // ---- mix + exp * invl -> Ebuf ----
    {
      float dv0[12], dv1[12];
      #pragma unroll
      for (int h = 0; h < 12; ++h) {
        ushort2 dp = *(const ushort2*)&Dbuf[h][i_mix][jp * 2];
        dv0[h] = bf16_to_f32(dp.x);
        dv1[h] = bf16_to_f32(dp.y);
      }
      #pragma unroll
      for (int g = 0; g < 12; ++g) {
        float m0 = 0.f, m1 = 0.f;
        #pragma unroll
        for (int h = 0; h < 12; ++h) {
          const float wgt = mpre_t[g * 12 + h];
          m0 += wgt * dv0[h]; m1 += wgt * dv1[h];
        }
        m0 = __expf(m0) * il[g];
        m1 = __expf(m1) * il[g];
        ushort2 ev;
        ev.x = f32_to_bf16_rne(m0);
        ev.y = f32_to_bf16_rne(m1);
        *(ushort2*)&Ebuf[g][i_mix][jp * 2] = ev;
      }
    }
    __syncthreads();  // Ebuf ready

    // ---- P'' = mpost x e~ -> Pbuf (wave's 3 g2) ----
    {
      float p[3][8];
      #pragma unroll
      for (int r = 0; r < 3; ++r)
        #pragma unroll
        for (int jj = 0; jj < 8; ++jj) p[r][jj] = 0.f;
      #pragma unroll
      for (int g = 0; g < 12; ++g) {
        ushort8_t ev = *(const ushort8_t*)&Ebuf[g][i_mix][jslot * 8];
        #pragma unroll
        for (int jj = 0; jj < 8; ++jj) {
          float ef = bf16_to_f32(ev[jj]);
          p[0][jj] += wpost[0][g] * ef;
          p[1][jj] += wpost[1][g] * ef;
          p[2][jj] += wpost[2][g] * ef;
        }
      }
      #pragma unroll
      for (int r = 0; r < 3; ++r) {
        ushort8_t pv;
        #pragma unroll
        for (int jj = 0; jj < 8; ++jj) pv[jj] = f32_to_bf16_rne(p[r][jj]);
        *(ushort8_t*)&Pbuf[(w * 3 + r) * 512 + i_mix * 32 + ((jslot ^ swz(i_mix)) << 3)] = pv;
      }
    }
    __syncthreads();  // P ready

    // ---- PV: A from Pbuf, B (V) direct from global ----
    #pragma unroll
    for (int gl = 0; gl < 3; ++gl) {
      const int g2 = w * 3 + gl;
      short8_t af = *(const short8_t*)&Pbuf[g2 * 512 + r15 * 32 + ((q ^ swz(r15)) << 3)];
      #pragma unroll
      for (int df = 0; df < 4; ++df) {
        short8_t bv = *(const short8_t*)&Vt[vbase + (long)(g2 * 64 + df * 16 + r15) * 1024 +
                                            j0 + q * 8];
        acc[gl][df] = __builtin_amdgcn_mfma_f32_16x16x32_bf16(af, bv, acc[gl][df], 0, 0, 0);
      }
    }
  }

  unsigned short* AOp = jh ? AOp1 : AOp0;
  #pragma unroll
  for (int gl = 0; gl < 3; ++gl) {
    const int g2 = w * 3 + gl;
    #pragma unroll
    for (int df = 0; df < 4; ++df)
      #pragma unroll
      for (int e = 0; e < 4; ++e) {
        int row = it * 16 + q * 4 + e;
        int col = g2 * 64 + df * 16 + r15;
        AOp[(long)(b * 1024 + row) * 768 + col] = f32_to_bf16_rne(acc[gl][df][e]);
      }
  }
}

// ---------------- host launch ----------------
extern "C" void kernel_launch(void* const* d_in, const int* in_sizes, int n_in,
                              void* d_out, int out_size, void* d_ws, size_t ws_size,
                              hipStream_t stream) {
  const float* x        = (const float*)d_in[0];
  const float* W_q      = (const float*)d_in[1];
  const float* W_kv     = (const float*)d_in[2];
  const float* mix_pre  = (const float*)d_in[3];
  const float* mix_post = (const float*)d_in[4];
  const float* W_out    = (const float*)d_in[5];
  const float* b_out    = (const float*)d_in[6];
  float* out = (float*)d_out;

  char* p = (char*)d_ws;
  auto alloc = [&](size_t bytes) { char* r = p; p += (bytes + 255) & ~(size_t)255; return r; };
  unsigned short* xb    = (unsigned short*)alloc(8192ull * 768 * 2);
  unsigned short* WqT   = (unsigned short*)alloc(768ull * 768 * 2);
  unsigned short* WkvT  = (unsigned short*)alloc(1536ull * 768 * 2);
  unsigned short* WoutT = (unsigned short*)alloc(768ull * 768 * 2);
  unsigned short* Qb    = (unsigned short*)alloc(8192ull * 768 * 2);
  unsigned short* KVb   = (unsigned short*)alloc(8192ull * 1536 * 2);
  unsigned short* Vt    = (unsigned short*)alloc(8ull * 12 * 64 * 1024 * 2);
  unsigned short* AOp0  = (unsigned short*)alloc(8192ull * 768 * 2);
  unsigned short* AOp1  = (unsigned short*)alloc(8192ull * 768 * 2);
  float*          Lpart = (float*)alloc(8ull * 32 * 12 * 1024 * 4);   // 12.6 MB
  float*          invl  = (float*)alloc(8ull * 12 * 1024 * 4);

  // 1) casts / transposes
  cast_x_kernel<<<6144, 256, 0, stream>>>((const float4*)x, (ushort4*)xb, 8192 * 768 / 4);
  transpose_cast_kernel<<<dim3(24, 24), 256, 0, stream>>>(W_q, WqT, 768, 768);
  transpose_cast_kernel<<<dim3(48, 24), 256, 0, stream>>>(W_kv, WkvT, 768, 1536);
  transpose_cast_kernel<<<dim3(24, 24), 256, 0, stream>>>(W_out, WoutT, 768, 768);

  // 2) projections
  gemm_nt<128, 128, false, false, false><<<dim3(6, 64), 256, 0, stream>>>(
      xb, nullptr, 768, WqT, 768, Qb, 768, nullptr, 8192, 768, 768);
  gemm_nt<128, 128, false, false, false><<<dim3(12, 64), 256, 0, stream>>>(
      xb, nullptr, 768, WkvT, 768, KVb, 1536, nullptr, 8192, 1536, 768);

  // 3) V transpose (linear)
  transpose_v_kernel<<<dim3(16, 12, 8), 256, 0, stream>>>(KVb, Vt);

  // 4) attention middle: all 8 batches, 3 dispatches, no E materialization
  qk_sum_kernel<<<dim3(32, 32, 8), 256, 0, stream>>>(Qb, KVb, mix_pre, Lpart);
  lsum_kernel<<<384, 256, 0, stream>>>(Lpart, invl, 8);
  fused_pv_kernel<<<dim3(64, 2, 8), 256, 0, stream>>>(Qb, KVb, Vt, invl, mix_pre, mix_post,
                                                      AOp0, AOp1);

  // 5) out = (AOp0 + AOp1) @ WoutT^T + b_out (fp32 out)
  gemm_nt<128, 128, true, true, true><<<dim3(6, 64), 256, 0, stream>>>(
      AOp0, AOp1, 768, WoutT, 768, out, 768, b_out, 8192, 768, 768);
}

// Round 13
// 722.543 us; speedup vs baseline: 1.1755x; 1.1755x over previous
//
#include <hip/hip_runtime.h>
#include <hip/hip_bf16.h>

typedef __attribute__((ext_vector_type(8))) short short8_t;
typedef __attribute__((ext_vector_type(8))) unsigned short ushort8_t;
typedef __attribute__((ext_vector_type(4))) float f32x4;

#define SCALE 0.125f   // 64^-0.5

__device__ __forceinline__ unsigned short f32_to_bf16_rne(float f) {
  unsigned int u = __float_as_uint(f);
  unsigned int r = 0x7FFFu + ((u >> 16) & 1u);
  return (unsigned short)((u + r) >> 16);
}
__device__ __forceinline__ float bf16_to_f32(unsigned short s) {
  return __uint_as_float((unsigned)s << 16);
}
// bank-spread swizzle for 64B rows (32 j * bf16): slot' = slot ^ swz(row)
__device__ __forceinline__ int swz(int i) { return (i + (i >> 2)) & 3; }

// ---------------- cast x (fp32 -> bf16) ----------------
__global__ __launch_bounds__(256) void cast_x_kernel(const float4* __restrict__ in,
                                                     ushort4* __restrict__ out, int n4) {
  int i = blockIdx.x * 256 + threadIdx.x;
  if (i < n4) {
    float4 v = in[i];
    ushort4 o;
    o.x = f32_to_bf16_rne(v.x); o.y = f32_to_bf16_rne(v.y);
    o.z = f32_to_bf16_rne(v.z); o.w = f32_to_bf16_rne(v.w);
    out[i] = o;
  }
}

// ---------------- transpose + cast weights: in R x C fp32 -> out C x R bf16 ----------------
__global__ __launch_bounds__(256) void transpose_cast_kernel(const float* __restrict__ in,
                                                             unsigned short* __restrict__ out,
                                                             int R, int C) {
  __shared__ float tile[32][33];
  int c0 = blockIdx.x * 32, r0 = blockIdx.y * 32;
  int tx = threadIdx.x & 31, ty = threadIdx.x >> 5;  // 32 x 8
  #pragma unroll
  for (int i = ty; i < 32; i += 8)
    tile[i][tx] = in[(long)(r0 + i) * C + c0 + tx];
  __syncthreads();
  #pragma unroll
  for (int i = ty; i < 32; i += 8)
    out[(long)(c0 + i) * R + r0 + tx] = f32_to_bf16_rne(tile[tx][i]);
}

// ---------------- transpose V (LINEAR j): Vt[b][h][d][j] = KV[b*1024+j][768+h*64+d] ----------------
__global__ __launch_bounds__(256) void transpose_v_kernel(const unsigned short* __restrict__ KV,
                                                          unsigned short* __restrict__ Vt) {
  __shared__ unsigned short tile[64][72];
  const int j0 = blockIdx.x * 64, h = blockIdx.y, b = blockIdx.z;
  const int tid = threadIdx.x;
  for (int c = tid; c < 512; c += 256) {
    int j = c >> 3, dp = (c & 7) * 8;
    *(ushort8_t*)&tile[j][dp] =
        *(const ushort8_t*)&KV[(long)(b * 1024 + j0 + j) * 1536 + 768 + h * 64 + dp];
  }
  __syncthreads();
  for (int c = tid; c < 512; c += 256) {
    int d = c >> 3, jp = (c & 7) * 8;
    ushort8_t v;
    #pragma unroll
    for (int t = 0; t < 8; t++) v[t] = tile[jp + t][d];
    *(ushort8_t*)&Vt[((long)(b * 12 + h) * 64 + d) * 1024 + j0 + jp] = v;
  }
}

// ---------------- NT GEMM (projections / out-proj). SUM2: A := A + A2 (bf16) ----------------
template <int BM, int BN, bool OUT_F32, bool BIAS, bool SUM2>
__global__ __launch_bounds__(256) void gemm_nt(const unsigned short* __restrict__ A,
                                               const unsigned short* __restrict__ A2, int lda,
                                               const unsigned short* __restrict__ B, int ldb,
                                               void* __restrict__ Cv, int ldc,
                                               const float* __restrict__ bias,
                                               int M, int N, int K) {
  constexpr int BK = 32;
  constexpr int LDT = BK + 8;
  __shared__ unsigned short As[BM][LDT];
  __shared__ unsigned short Bs[BN][LDT];
  const int m0 = blockIdx.y * BM;
  const int n0 = blockIdx.x * BN;
  const int tid = threadIdx.x;
  const int lane = tid & 63;
  const int w = tid >> 6;
  constexpr int WM = BM / 2, WN = BN / 2;
  constexpr int FM = WM / 16, FN = WN / 16;
  const int wr = w >> 1, wc = w & 1;

  f32x4 acc[FM][FN];
  #pragma unroll
  for (int a = 0; a < FM; a++)
    #pragma unroll
    for (int b2 = 0; b2 < FN; b2++) acc[a][b2] = (f32x4){0.f, 0.f, 0.f, 0.f};

  const int rl = lane & 15;
  const int kq = (lane >> 4) * 8;

  for (int k0 = 0; k0 < K; k0 += BK) {
    __syncthreads();
    for (int c = tid; c < BM * (BK / 8); c += 256) {
      int row = c >> 2, kp = (c & 3) * 8;
      ushort8_t v = *(const ushort8_t*)&A[(long)(m0 + row) * lda + k0 + kp];
      if (SUM2) {
        ushort8_t v2 = *(const ushort8_t*)&A2[(long)(m0 + row) * lda + k0 + kp];
        #pragma unroll
        for (int x = 0; x < 8; ++x)
          v[x] = f32_to_bf16_rne(bf16_to_f32(v[x]) + bf16_to_f32(v2[x]));
      }
      *(ushort8_t*)&As[row][kp] = v;
    }
    for (int c = tid; c < BN * (BK / 8); c += 256) {
      int row = c >> 2, kp = (c & 3) * 8;
      *(ushort8_t*)&Bs[row][kp] = *(const ushort8_t*)&B[(long)(n0 + row) * ldb + k0 + kp];
    }
    __syncthreads();
    short8_t af[FM], bfr[FN];
    #pragma unroll
    for (int fm = 0; fm < FM; fm++) af[fm] = *(const short8_t*)&As[wr * WM + fm * 16 + rl][kq];
    #pragma unroll
    for (int fn = 0; fn < FN; fn++) bfr[fn] = *(const short8_t*)&Bs[wc * WN + fn * 16 + rl][kq];
    #pragma unroll
    for (int fm = 0; fm < FM; fm++)
      #pragma unroll
      for (int fn = 0; fn < FN; fn++)
        acc[fm][fn] = __builtin_amdgcn_mfma_f32_16x16x32_bf16(af[fm], bfr[fn], acc[fm][fn], 0, 0, 0);
  }

  const int rq4 = (lane >> 4) * 4;
  #pragma unroll
  for (int fm = 0; fm < FM; fm++)
    #pragma unroll
    for (int fn = 0; fn < FN; fn++)
      #pragma unroll
      for (int j = 0; j < 4; j++) {
        int row = m0 + wr * WM + fm * 16 + rq4 + j;
        int col = n0 + wc * WN + fn * 16 + rl;
        float v = acc[fm][fn][j];
        if (BIAS) v += bias[col];
        if (OUT_F32)
          ((float*)Cv)[(long)row * ldc + col] = v;
        else
          ((unsigned short*)Cv)[(long)row * ldc + col] = f32_to_bf16_rne(v);
      }
}

// ---------------- Pass A: QK^T -> dots(LDS) -> mix+exp -> row sums ONLY ----------------
__global__ __launch_bounds__(256, 1) void qk_sum_kernel(
    const unsigned short* __restrict__ Qb, const unsigned short* __restrict__ KVb,
    const float* __restrict__ mix_pre, float* __restrict__ Lpart) {
  __shared__ unsigned short Dbuf[12 * 32 * 44];  // 33 KB dots (bf16)
  __shared__ float mpre_t[144];                  // transposed [g][h], *SCALE
  const int jt = blockIdx.x, it2 = blockIdx.y, zc = blockIdx.z;
  const int b = zc;
  const int tid = threadIdx.x, lane = tid & 63, w = tid >> 6;
  const int r15 = lane & 15, q = lane >> 4;
  if (tid < 144) {
    int g = tid / 12, h = tid - g * 12;
    mpre_t[tid] = mix_pre[h * 12 + g] * SCALE;
  }

  const int isel = w >> 1, jsel = w & 1;
  const long qrow = (long)(b * 1024 + it2 * 32 + isel * 16 + r15) * 768 + q * 8;
  const long krow = (long)(b * 1024 + jt * 32 + jsel * 16 + r15) * 1536 + q * 8;
  const int jcol = jsel * 16 + r15;
  for (int h = 0; h < 12; ++h) {
    const int kb = h * 64;
    short8_t a0 = *(const short8_t*)&Qb[qrow + kb];
    short8_t a1 = *(const short8_t*)&Qb[qrow + kb + 32];
    short8_t b0 = *(const short8_t*)&KVb[krow + kb];
    short8_t b1 = *(const short8_t*)&KVb[krow + kb + 32];
    f32x4 h0 = {0.f, 0.f, 0.f, 0.f};
    h0 = __builtin_amdgcn_mfma_f32_16x16x32_bf16(a0, b0, h0, 0, 0, 0);
    h0 = __builtin_amdgcn_mfma_f32_16x16x32_bf16(a1, b1, h0, 0, 0, 0);
    #pragma unroll
    for (int e = 0; e < 4; ++e) {
      int il = isel * 16 + q * 4 + e;
      Dbuf[h * 1408 + il * 44 + jcol] = f32_to_bf16_rne(h0[e]);
    }
  }
  __syncthreads();

  const int i_loc = tid >> 3;   // 0..31
  const int jg = tid & 7;       // j quad

  float dvf[12][4];
  #pragma unroll
  for (int h = 0; h < 12; ++h) {
    ushort4 dv = *(const ushort4*)&Dbuf[h * 1408 + i_loc * 44 + jg * 4];
    dvf[h][0] = bf16_to_f32(dv.x); dvf[h][1] = bf16_to_f32(dv.y);
    dvf[h][2] = bf16_to_f32(dv.z); dvf[h][3] = bf16_to_f32(dv.w);
  }

  #pragma unroll
  for (int g = 0; g < 12; ++g) {
    float a0 = 0.f, a1 = 0.f, a2 = 0.f, a3 = 0.f;
    #pragma unroll
    for (int h = 0; h < 12; ++h) {
      const float wgt = mpre_t[g * 12 + h];
      a0 += wgt * dvf[h][0]; a1 += wgt * dvf[h][1];
      a2 += wgt * dvf[h][2]; a3 += wgt * dvf[h][3];
    }
    a0 = __expf(a0); a1 = __expf(a1); a2 = __expf(a2); a3 = __expf(a3);
    float s = a0 + a1 + a2 + a3;
    s += __shfl_xor(s, 1);
    s += __shfl_xor(s, 2);
    s += __shfl_xor(s, 4);
    if (jg == (g & 7))
      Lpart[((long)(zc * 32 + jt) * 12 + g) * 1024 + it2 * 32 + i_loc] = s;
  }
}

// ---------------- Y: invl[zc][g][i] = 1 / sum_jt Lpart ----------------
__global__ __launch_bounds__(256) void lsum_kernel(const float* __restrict__ Lpart,
                                                   float* __restrict__ invl, int nb) {
  int id = blockIdx.x * 256 + threadIdx.x;
  if (id >= nb * 12288) return;
  int z = id / 12288, r = id - z * 12288;
  float s = 0.f;
  #pragma unroll 4
  for (int jt = 0; jt < 32; ++jt) s += Lpart[((long)(z * 32 + jt)) * 12288 + r];
  invl[id] = 1.f / s;
}

// ---------------- Pass B v2: fused QK-recompute + mix + exp*invl + mpost + PV ----------------
// Latency fixes vs round 12 (553us, nothing saturated -> barrier/latency-bound):
//  1. Barrier #3 REMOVED: Pbuf g2-trio is written and read by the SAME wave --
//     intra-wave LDS RAW needs only lgkmcnt, no block barrier. 48 -> 32 barriers.
//  2. V prefetched into vreg[12] right after bar1; bar2's implicit vmcnt(0)
//     drain delivers them exactly when PV starts -- mix phase hides the gather.
//  3. wpost (36 VGPR in r12) -> LDS wave-uniform broadcasts (mpost_t), paying
//     for vreg's +48. (256,1) keeps the allocator unconstrained (r6-r8 lesson).
__global__ __launch_bounds__(256, 1) void fused_pv_kernel(
    const unsigned short* __restrict__ Qb, const unsigned short* __restrict__ KVb,
    const unsigned short* __restrict__ Vt, const float* __restrict__ invl,
    const float* __restrict__ mix_pre, const float* __restrict__ mix_post,
    unsigned short* __restrict__ AOp0, unsigned short* __restrict__ AOp1) {
  __shared__ unsigned short Dbuf[12][16][34];  // raw dots (pad 34)
  __shared__ unsigned short Ebuf[12][16][40];  // e~ = exp*invl (stride 80B)
  __shared__ unsigned short Pbuf[12 * 512];    // P'' [g2][16 i][32 j] swizzled
  __shared__ float mpre_t[144];                // [g][h] * SCALE
  __shared__ float mpost_t[144];               // [g2][g]
  const int it = blockIdx.x, jh = blockIdx.y, zc = blockIdx.z;
  const int b = zc;
  const int tid = threadIdx.x, lane = tid & 63, w = tid >> 6;
  const int r15 = lane & 15, q = lane >> 4;
  if (tid < 144) {
    int a_ = tid / 12, c_ = tid - a_ * 12;
    mpre_t[tid] = mix_pre[c_ * 12 + a_] * SCALE;
    mpost_t[tid] = mix_post[c_ * 12 + a_];
  }

  // hoisted QK A-frags: wave's h-trio, rows i = it*16 + r15
  const int h0 = w * 3;
  const long qbase = (long)(b * 1024 + it * 16 + r15) * 768;
  short8_t qf[3][2];
  #pragma unroll
  for (int hh = 0; hh < 3; ++hh) {
    qf[hh][0] = *(const short8_t*)&Qb[qbase + (h0 + hh) * 64 + q * 8];
    qf[hh][1] = *(const short8_t*)&Qb[qbase + (h0 + hh) * 64 + 32 + q * 8];
  }

  const int i_mix = tid & 15;
  const int jp = tid >> 4;          // 0..15 -> j-pair
  const int jslot = (tid >> 4) & 3; // P''-stage 8-j slot (in-wave)
  float il[12];
  #pragma unroll
  for (int g = 0; g < 12; ++g) il[g] = invl[(zc * 12 + g) * 1024 + it * 16 + i_mix];

  f32x4 acc[3][4];
  #pragma unroll
  for (int gl = 0; gl < 3; ++gl)
    #pragma unroll
    for (int df = 0; df < 4; ++df) acc[gl][df] = (f32x4){0.f, 0.f, 0.f, 0.f};

  const long vbase = (long)(b * 12) * 64 * 1024;

  for (int t = 0; t < 16; ++t) {
    const int j0 = (jh * 16 + t) * 32;

    // ---- QK: dots for wave's 3 h over 16i x 32j ----
    #pragma unroll
    for (int hh = 0; hh < 3; ++hh) {
      #pragma unroll
      for (int jhf = 0; jhf < 2; ++jhf) {
        const long kr = (long)(b * 1024 + j0 + jhf * 16 + r15) * 1536 + (h0 + hh) * 64 + q * 8;
        short8_t b0 = *(const short8_t*)&KVb[kr];
        short8_t b1 = *(const short8_t*)&KVb[kr + 32];
        f32x4 d = {0.f, 0.f, 0.f, 0.f};
        d = __builtin_amdgcn_mfma_f32_16x16x32_bf16(qf[hh][0], b0, d, 0, 0, 0);
        d = __builtin_amdgcn_mfma_f32_16x16x32_bf16(qf[hh][1], b1, d, 0, 0, 0);
        #pragma unroll
        for (int e = 0; e < 4; ++e)
          Dbuf[h0 + hh][q * 4 + e][jhf * 16 + r15] = f32_to_bf16_rne(d[e]);
      }
    }
    __syncthreads();  // bar1: Dbuf ready; all waves past P''(t-1) -> Ebuf free

    // ---- V prefetch (consumed after bar2; mix phase hides the gather) ----
    short8_t vreg[12];
    #pragma unroll
    for (int gl = 0; gl < 3; ++gl)
      #pragma unroll
      for (int df = 0; df < 4; ++df)
        vreg[gl * 4 + df] = *(const short8_t*)&Vt[vbase +
            (long)((h0 + gl) * 64 + df * 16 + r15) * 1024 + j0 + q * 8];

    // ---- mix + exp * invl -> Ebuf ----
    {
      float dv0[12], dv1[12];
      #pragma unroll
      for (int h = 0; h < 12; ++h) {
        ushort2 dp = *(const ushort2*)&Dbuf[h][i_mix][jp * 2];
        dv0[h] = bf16_to_f32(dp.x);
        dv1[h] = bf16_to_f32(dp.y);
      }
      #pragma unroll
      for (int g = 0; g < 12; ++g) {
        float m0 = 0.f, m1 = 0.f;
        #pragma unroll
        for (int h = 0; h < 12; ++h) {
          const float wgt = mpre_t[g * 12 + h];
          m0 += wgt * dv0[h]; m1 += wgt * dv1[h];
        }
        m0 = __expf(m0) * il[g];
        m1 = __expf(m1) * il[g];
        ushort2 ev;
        ev.x = f32_to_bf16_rne(m0);
        ev.y = f32_to_bf16_rne(m1);
        *(ushort2*)&Ebuf[g][i_mix][jp * 2] = ev;
      }
    }
    __syncthreads();  // bar2: Ebuf ready; vmcnt drain -> vreg ready

    // ---- P'' = mpost x e~ -> Pbuf (wave-private g2-trio; NO barrier after) ----
    {
      float p[3][8];
      #pragma unroll
      for (int r = 0; r < 3; ++r)
        #pragma unroll
        for (int jj = 0; jj < 8; ++jj) p[r][jj] = 0.f;
      #pragma unroll
      for (int g = 0; g < 12; ++g) {
        ushort8_t ev = *(const ushort8_t*)&Ebuf[g][i_mix][jslot * 8];
        float w0 = mpost_t[(h0 + 0) * 12 + g];
        float w1 = mpost_t[(h0 + 1) * 12 + g];
        float w2 = mpost_t[(h0 + 2) * 12 + g];
        #pragma unroll
        for (int jj = 0; jj < 8; ++jj) {
          float ef = bf16_to_f32(ev[jj]);
          p[0][jj] += w0 * ef;
          p[1][jj] += w1 * ef;
          p[2][jj] += w2 * ef;
        }
      }
      #pragma unroll
      for (int r = 0; r < 3; ++r) {
        ushort8_t pv;
        #pragma unroll
        for (int jj = 0; jj < 8; ++jj) pv[jj] = f32_to_bf16_rne(p[r][jj]);
        *(ushort8_t*)&Pbuf[(w * 3 + r) * 512 + i_mix * 32 + ((jslot ^ swz(i_mix)) << 3)] = pv;
      }
    }

    // ---- PV: A from Pbuf (same wave, lgkmcnt only), B = prefetched vreg ----
    #pragma unroll
    for (int gl = 0; gl < 3; ++gl) {
      const int g2 = w * 3 + gl;
      short8_t af = *(const short8_t*)&Pbuf[g2 * 512 + r15 * 32 + ((q ^ swz(r15)) << 3)];
      #pragma unroll
      for (int df = 0; df < 4; ++df)
        acc[gl][df] = __builtin_amdgcn_mfma_f32_16x16x32_bf16(af, vreg[gl * 4 + df],
                                                              acc[gl][df], 0, 0, 0);
    }
  }

  unsigned short* AOp = jh ? AOp1 : AOp0;
  #pragma unroll
  for (int gl = 0; gl < 3; ++gl) {
    const int g2 = w * 3 + gl;
    #pragma unroll
    for (int df = 0; df < 4; ++df)
      #pragma unroll
      for (int e = 0; e < 4; ++e) {
        int row = it * 16 + q * 4 + e;
        int col = g2 * 64 + df * 16 + r15;
        AOp[(long)(b * 1024 + row) * 768 + col] = f32_to_bf16_rne(acc[gl][df][e]);
      }
  }
}

// ---------------- host launch ----------------
extern "C" void kernel_launch(void* const* d_in, const int* in_sizes, int n_in,
                              void* d_out, int out_size, void* d_ws, size_t ws_size,
                              hipStream_t stream) {
  const float* x        = (const float*)d_in[0];
  const float* W_q      = (const float*)d_in[1];
  const float* W_kv     = (const float*)d_in[2];
  const float* mix_pre  = (const float*)d_in[3];
  const float* mix_post = (const float*)d_in[4];
  const float* W_out    = (const float*)d_in[5];
  const float* b_out    = (const float*)d_in[6];
  float* out = (float*)d_out;

  char* p = (char*)d_ws;
  auto alloc = [&](size_t bytes) { char* r = p; p += (bytes + 255) & ~(size_t)255; return r; };
  unsigned short* xb    = (unsigned short*)alloc(8192ull * 768 * 2);
  unsigned short* WqT   = (unsigned short*)alloc(768ull * 768 * 2);
  unsigned short* WkvT  = (unsigned short*)alloc(1536ull * 768 * 2);
  unsigned short* WoutT = (unsigned short*)alloc(768ull * 768 * 2);
  unsigned short* Qb    = (unsigned short*)alloc(8192ull * 768 * 2);
  unsigned short* KVb   = (unsigned short*)alloc(8192ull * 1536 * 2);
  unsigned short* Vt    = (unsigned short*)alloc(8ull * 12 * 64 * 1024 * 2);
  unsigned short* AOp0  = (unsigned short*)alloc(8192ull * 768 * 2);
  unsigned short* AOp1  = (unsigned short*)alloc(8192ull * 768 * 2);
  float*          Lpart = (float*)alloc(8ull * 32 * 12 * 1024 * 4);
  float*          invl  = (float*)alloc(8ull * 12 * 1024 * 4);

  // 1) casts / transposes
  cast_x_kernel<<<6144, 256, 0, stream>>>((const float4*)x, (ushort4*)xb, 8192 * 768 / 4);
  transpose_cast_kernel<<<dim3(24, 24), 256, 0, stream>>>(W_q, WqT, 768, 768);
  transpose_cast_kernel<<<dim3(48, 24), 256, 0, stream>>>(W_kv, WkvT, 768, 1536);
  transpose_cast_kernel<<<dim3(24, 24), 256, 0, stream>>>(W_out, WoutT, 768, 768);

  // 2) projections
  gemm_nt<128, 128, false, false, false><<<dim3(6, 64), 256, 0, stream>>>(
      xb, nullptr, 768, WqT, 768, Qb, 768, nullptr, 8192, 768, 768);
  gemm_nt<128, 128, false, false, false><<<dim3(12, 64), 256, 0, stream>>>(
      xb, nullptr, 768, WkvT, 768, KVb, 1536, nullptr, 8192, 1536, 768);

  // 3) V transpose (linear)
  transpose_v_kernel<<<dim3(16, 12, 8), 256, 0, stream>>>(KVb, Vt);

  // 4) attention middle: 3 dispatches, no E materialization
  qk_sum_kernel<<<dim3(32, 32, 8), 256, 0, stream>>>(Qb, KVb, mix_pre, Lpart);
  lsum_kernel<<<384, 256, 0, stream>>>(Lpart, invl, 8);
  fused_pv_kernel<<<dim3(64, 2, 8), 256, 0, stream>>>(Qb, KVb, Vt, invl, mix_pre, mix_post,
                                                      AOp0, AOp1);

  // 5) out = (AOp0 + AOp1) @ WoutT^T + b_out (fp32 out)
  gemm_nt<128, 128, true, true, true><<<dim3(6, 64), 256, 0, stream>>>(
      AOp0, AOp1, 768, WoutT, 768, out, 768, b_out, 8192, 768, 768);
}